// Round 9
// baseline (934.026 us; speedup 1.0000x reference)
//
#include <hip/hip_runtime.h>
#include <cstdint>

// AttentionPooling — wave-autonomous single-HBM-pass.
// w_i = exp(s_i) directly (|s| <= ||W2||_1+|b2| ~ 11.5, safe in f32: no max
// subtraction, no online rescale, NO barriers in the main loop).
// Per 32-row tile per wave: A-frags from global (x read once), MFMA vs W1
// (staged once in 64KB LDS), score epilogue, w broadcast, in-register
// weighted accumulation from the same A-frags. Finalize per graph via LDS.

#define H_DIM 256
#define HID   128

typedef _Float16 half8 __attribute__((ext_vector_type(8)));
typedef float floatx4 __attribute__((ext_vector_type(4)));

__device__ __forceinline__ float fast_tanh(float y) {
    float e2 = __expf(2.0f * y);
    return 1.0f - 2.0f / (e2 + 1.0f);
}

// ---------------------------------------------------------------- prep_w1
// idx = ((nt*8 + ks)*64 + lane)*8 + j  <->  W1[k][n], k = ks*32+(lane>>4)*8+j,
// n = nt*16 + (lane&15)
__global__ void prep_w1(const float* __restrict__ W1, _Float16* __restrict__ w1h) {
    int idx = blockIdx.x * blockDim.x + threadIdx.x;
    if (idx >= 8 * 8 * 64 * 8) return;
    int j  = idx & 7;
    int l  = (idx >> 3) & 63;
    int ks = (idx >> 9) & 7;
    int nt = idx >> 12;
    int k = ks * 32 + ((l >> 4) << 3) + j;
    int n = nt * 16 + (l & 15);
    w1h[idx] = (_Float16)W1[k * HID + n];
}

// ---------------------------------------------------------------- fused
// grid = ceil(B/4) blocks x 512 threads (8 waves); block handles 4 graphs.
__global__ __launch_bounds__(512, 2) void fused_kernel(
    const float* __restrict__ x, const _Float16* __restrict__ w1h,
    const float* __restrict__ b1, const float* __restrict__ W2,
    const float* __restrict__ b2, const int* __restrict__ batch,
    float* __restrict__ out, int N, int B)
{
    __shared__ __align__(16) _Float16 w1s[32768];   // 64KB, B-frag order
    __shared__ float scr[8 * H_DIM + 8];            // cross-wave reduce scratch

    int tid = threadIdx.x;
    {   // stage W1 once
        const uint4* s = (const uint4*)w1h;
        uint4* d = (uint4*)w1s;
#pragma unroll
        for (int i = 0; i < 8; ++i) d[tid + i * 512] = s[tid + i * 512];
    }
    __syncthreads();

    int wv = tid >> 6, lane = tid & 63, g = lane >> 4, c = lane & 15;

    float b1r[8], w2r[8];
#pragma unroll
    for (int nt = 0; nt < 8; ++nt) {
        b1r[nt] = b1[nt * 16 + c];
        w2r[nt] = W2[nt * 16 + c];
    }
    float b2v = b2[0];

    for (int gi = 0; gi < 4; ++gi) {
        int b = blockIdx.x * 4 + gi;
        if (b >= B) break;

        // segment bounds (batch sorted)
        int lo = 0, hi = N;
        while (lo < hi) { int m = (lo + hi) >> 1; if (batch[m] < b) lo = m + 1; else hi = m; }
        int start = lo; hi = N;
        while (lo < hi) { int m = (lo + hi) >> 1; if (batch[m] <= b) lo = m + 1; else hi = m; }
        int end = lo;
        int seglen = end - start;

        if (seglen <= 0) {               // uniform branch; ref output is 0
            if (tid < H_DIM) out[(size_t)b * H_DIM + tid] = 0.0f;
            __syncthreads();
            continue;
        }
        int ntiles = (seglen + 31) >> 5;

        float accv[8][8];                 // accv[ks][j]: col = ks*32+g*8+j
#pragma unroll
        for (int ks = 0; ks < 8; ++ks)
#pragma unroll
            for (int j = 0; j < 8; ++j) accv[ks][j] = 0.0f;
        float zp = 0.0f;

        for (int t = wv; t < ntiles; t += 8) {
            int r0 = start + t * 32;
            int ra = r0 + c, rb = r0 + 16 + c;     // this lane's two rows
            int rl = end - 1;
            int ca = ra <= rl ? ra : rl;
            int cb = rb <= rl ? rb : rl;
            const float* pa = x + (size_t)ca * H_DIM + g * 8;
            const float* pb = x + (size_t)cb * H_DIM + g * 8;

            // ---- A-fragments, mt=0 (16 loads in flight, then cvt)
            float4 qa[16];
#pragma unroll
            for (int ks = 0; ks < 8; ++ks) {
                qa[2 * ks]     = *(const float4*)(pa + ks * 32);
                qa[2 * ks + 1] = *(const float4*)(pa + ks * 32 + 4);
            }
            half8 af0[8];
#pragma unroll
            for (int ks = 0; ks < 8; ++ks) {
                half8 h;
                h[0] = (_Float16)qa[2 * ks].x;     h[1] = (_Float16)qa[2 * ks].y;
                h[2] = (_Float16)qa[2 * ks].z;     h[3] = (_Float16)qa[2 * ks].w;
                h[4] = (_Float16)qa[2 * ks + 1].x; h[5] = (_Float16)qa[2 * ks + 1].y;
                h[6] = (_Float16)qa[2 * ks + 1].z; h[7] = (_Float16)qa[2 * ks + 1].w;
                af0[ks] = h;
            }
            // ---- A-fragments, mt=1
#pragma unroll
            for (int ks = 0; ks < 8; ++ks) {
                qa[2 * ks]     = *(const float4*)(pb + ks * 32);
                qa[2 * ks + 1] = *(const float4*)(pb + ks * 32 + 4);
            }
            half8 af1[8];
#pragma unroll
            for (int ks = 0; ks < 8; ++ks) {
                half8 h;
                h[0] = (_Float16)qa[2 * ks].x;     h[1] = (_Float16)qa[2 * ks].y;
                h[2] = (_Float16)qa[2 * ks].z;     h[3] = (_Float16)qa[2 * ks].w;
                h[4] = (_Float16)qa[2 * ks + 1].x; h[5] = (_Float16)qa[2 * ks + 1].y;
                h[6] = (_Float16)qa[2 * ks + 1].z; h[7] = (_Float16)qa[2 * ks + 1].w;
                af1[ks] = h;
            }

            // ---- scores: per hidden tile nt, K=256; epilogue folded in
            float p0[4] = {0, 0, 0, 0}, p1[4] = {0, 0, 0, 0};
#pragma unroll
            for (int nt = 0; nt < 8; ++nt) {
                floatx4 s0 = {0, 0, 0, 0}, s1 = {0, 0, 0, 0};
#pragma unroll
                for (int ks = 0; ks < 8; ++ks) {
                    half8 bf = *(const half8*)&w1s[((nt * 8 + ks) * 64 + lane) * 8];
                    s0 = __builtin_amdgcn_mfma_f32_16x16x32_f16(af0[ks], bf, s0, 0, 0, 0);
                    s1 = __builtin_amdgcn_mfma_f32_16x16x32_f16(af1[ks], bf, s1, 0, 0, 0);
                }
#pragma unroll
                for (int r = 0; r < 4; ++r) {
                    p0[r] += fast_tanh(s0[r] + b1r[nt]) * w2r[nt];
                    p1[r] += fast_tanh(s1[r] + b1r[nt]) * w2r[nt];
                }
            }
            // reduce over the 16 cols (c) of each row-group
#pragma unroll
            for (int r = 0; r < 4; ++r) {
                p0[r] += __shfl_xor(p0[r], 1); p0[r] += __shfl_xor(p0[r], 2);
                p0[r] += __shfl_xor(p0[r], 4); p0[r] += __shfl_xor(p0[r], 8);
                p1[r] += __shfl_xor(p1[r], 1); p1[r] += __shfl_xor(p1[r], 2);
                p1[r] += __shfl_xor(p1[r], 4); p1[r] += __shfl_xor(p1[r], 8);
            }
            // broadcast: lane needs s of row (lane&15) [mt0] and 16+(lane&15) [mt1].
            // score s_{g'*4+r'} lives in lanes g'=row>>2 as reg p[row&3];
            // source lane = ((lane&15)>>2)*16 + (lane&3) has sel == its own (l&3).
            float sel0 = (lane & 1) ? p0[1] : p0[0];
            float t0b  = (lane & 1) ? p0[3] : p0[2];
            sel0 = (lane & 2) ? t0b : sel0;
            float sel1 = (lane & 1) ? p1[1] : p1[0];
            float t1b  = (lane & 1) ? p1[3] : p1[2];
            sel1 = (lane & 2) ? t1b : sel1;
            int src = ((lane & 15) >> 2) * 16 + (lane & 3);
            float s_a = __shfl(sel0, src) + b2v;
            float s_b = __shfl(sel1, src) + b2v;
            float w0 = (ra < end) ? __expf(s_a) : 0.0f;
            float w1 = (rb < end) ? __expf(s_b) : 0.0f;
            if (g == 0) zp += w0 + w1;     // each row counted once (lanes 0-15)

            // ---- in-register weighted accumulation (x already in af frags)
#pragma unroll
            for (int ks = 0; ks < 8; ++ks)
#pragma unroll
                for (int j = 0; j < 8; ++j)
                    accv[ks][j] += w0 * (float)af0[ks][j] + w1 * (float)af1[ks][j];
        }

        // ---- finalize graph: 16-lane reduce, cross-wave reduce via LDS
#pragma unroll
        for (int ks = 0; ks < 8; ++ks)
#pragma unroll
            for (int j = 0; j < 8; ++j) {
                float v = accv[ks][j];
                v += __shfl_xor(v, 1); v += __shfl_xor(v, 2);
                v += __shfl_xor(v, 4); v += __shfl_xor(v, 8);
                if (c == ((ks * 8 + j) & 15))
                    scr[wv * H_DIM + ks * 32 + g * 8 + j] = v;
            }
        float z = zp;
        z += __shfl_xor(z, 1);  z += __shfl_xor(z, 2);  z += __shfl_xor(z, 4);
        z += __shfl_xor(z, 8);  z += __shfl_xor(z, 16); z += __shfl_xor(z, 32);
        if (lane == 0) scr[8 * H_DIM + wv] = z;
        __syncthreads();
        if (tid < H_DIM) {
            float s = 0.0f;
#pragma unroll
            for (int w = 0; w < 8; ++w) s += scr[w * H_DIM + tid];
            float Z = 0.0f;
#pragma unroll
            for (int w = 0; w < 8; ++w) Z += scr[8 * H_DIM + w];
            out[(size_t)b * H_DIM + tid] = s / Z;
        }
        __syncthreads();   // scr reused by next graph
    }
}

// ---------------------------------------------------------------- launch
extern "C" void kernel_launch(void* const* d_in, const int* in_sizes, int n_in,
                              void* d_out, int out_size, void* d_ws, size_t ws_size,
                              hipStream_t stream) {
    const float* x    = (const float*)d_in[0];
    const float* W1   = (const float*)d_in[1];
    const float* b1   = (const float*)d_in[2];
    const float* W2   = (const float*)d_in[3];
    const float* b2   = (const float*)d_in[4];
    const int*   batch = (const int*)d_in[5];
    int N = in_sizes[5];
    int B = out_size / H_DIM;

    _Float16* w1h = (_Float16*)d_ws;   // 64KB frag-ordered W1

    prep_w1<<<32768 / 256, 256, 0, stream>>>(W1, w1h);
    int nblk = (B + 3) / 4;
    fused_kernel<<<nblk, 512, 0, stream>>>(x, w1h, b1, W2, b2, batch,
                                           (float*)d_out, N, B);
}

// Round 10
// 540.503 us; speedup vs baseline: 1.7281x; 1.7281x over previous
//
#include <hip/hip_runtime.h>
#include <cstdint>

// AttentionPooling — fused single-HBM-pass, R10.
// Key fixes vs R4-R9 (all counter-indicted):
//  * W1 B-frags in REGISTERS, one n-tile per wave (32 VGPR, loaded once):
//    eliminates the per-chunk W1 L2 stream that capped R5/R6/R9 at the L2
//    ceiling (~49 B/cy/CU).
//  * Light barriers (lgkmcnt-only + raw s_barrier): global prefetch loads
//    stay in flight across all barriers -> HBM duty cycle stays high.
//  * exp(s) without max subtraction (|s| <= ||W2||_1 + |b2| ~ 11.5, f32-safe):
//    no online rescale, no cross-chunk state.
//  * Register budget ~125: no spills (R9's 1.1GB spill writes).
// Per 64-row chunk: prefetch regs -> f16 LDS tile (XOR-swizzled, dbuf) ->
// MFMA scores -> w=exp(s) -> column pool from LDS. x read from HBM once.

#define H_DIM 256
#define HID   128
#define ROWS  64

typedef _Float16 half8 __attribute__((ext_vector_type(8)));
typedef float floatx4 __attribute__((ext_vector_type(4)));

__device__ __forceinline__ float fast_tanh(float y) {
    float e2 = __expf(2.0f * y);
    return 1.0f - 2.0f / (e2 + 1.0f);
}

__device__ __forceinline__ void light_barrier() {
    // drain LDS ops, then barrier. Does NOT drain vmcnt: global prefetch
    // loads (thread-private regs) legally stay in flight.
    asm volatile("s_waitcnt lgkmcnt(0)" ::: "memory");
    __builtin_amdgcn_s_barrier();
}

// ---------------------------------------------------------------- prep_w1
// idx = ((nt*8 + ks)*64 + lane)*8 + j  <->  W1[k][n], k = ks*32+(lane>>4)*8+j,
// n = nt*16 + (lane&15)
__global__ void prep_w1(const float* __restrict__ W1, _Float16* __restrict__ w1h) {
    int idx = blockIdx.x * blockDim.x + threadIdx.x;
    if (idx >= 8 * 8 * 64 * 8) return;
    int j  = idx & 7;
    int l  = (idx >> 3) & 63;
    int ks = (idx >> 9) & 7;
    int nt = idx >> 12;
    int k = ks * 32 + ((l >> 4) << 3) + j;
    int n = nt * 16 + (l & 15);
    w1h[idx] = (_Float16)W1[k * HID + n];
}

// ---------------------------------------------------------------- fused
// grid = B blocks x 512 threads (8 waves); block processes one graph.
__global__ __launch_bounds__(512, 2) void fused_kernel(
    const float* __restrict__ x, const _Float16* __restrict__ w1h,
    const float* __restrict__ b1, const float* __restrict__ W2,
    const float* __restrict__ b2, const int* __restrict__ batch,
    float* __restrict__ out, int N)
{
    __shared__ __align__(16) _Float16 xt[2][ROWS * H_DIM]; // 2 x 32KB, swizzled
    __shared__ float pbuf[8][ROWS];                        // 2KB; reused as scr
    __shared__ float wbuf[ROWS];

    int tid = threadIdx.x, b = blockIdx.x;
    int wv = tid >> 6, lane = tid & 63, g = lane >> 4, c = lane & 15;

    // segment bounds (batch sorted)
    int lo = 0, hi = N;
    while (lo < hi) { int m = (lo + hi) >> 1; if (batch[m] < b) lo = m + 1; else hi = m; }
    int start = lo; hi = N;
    while (lo < hi) { int m = (lo + hi) >> 1; if (batch[m] <= b) lo = m + 1; else hi = m; }
    int end = lo;
    int seglen = end - start;
    if (seglen <= 0) {
        if (tid < H_DIM) out[(size_t)b * H_DIM + tid] = 0.0f;
        return;
    }
    int nch = (seglen + ROWS - 1) / ROWS;

    // this wave's W1 n-tile (nt = wv), 8 k-step B-frags in registers (32 VGPR)
    half8 bfr[8];
#pragma unroll
    for (int ks = 0; ks < 8; ++ks)
        bfr[ks] = *(const half8*)&w1h[((wv * 8 + ks) * 64 + lane) * 8];
    float b1v = b1[wv * 16 + c];
    float w2v = W2[wv * 16 + c];
    float b2v = b2[0];

    int srow = tid >> 3, q = tid & 7;       // stage role: row, 32-col quarter
    int pcol = tid & 255, prh = tid >> 8;   // pool role: column, row half

    float acc = 0.0f;   // pooled sum for (pcol, row-half prh)
    float zp  = 0.0f;   // Z partial (wave-0 threads only)

    auto load = [&](float4* r, int t) {
        int cntt = seglen - t * ROWS; if (cntt > ROWS) cntt = ROWS;
        int lr = srow < cntt ? srow : cntt - 1;             // clamp tail
        const float* p = x + (size_t)(start + t * ROWS + lr) * H_DIM + q * 32;
#pragma unroll
        for (int i = 0; i < 8; ++i) r[i] = *(const float4*)(p + i * 4);
    };
    auto stage = [&](const float4* r, _Float16* xb) {
#pragma unroll
        for (int i8 = 0; i8 < 4; ++i8) {
            half8 hv;
            hv[0] = (_Float16)r[2 * i8].x;     hv[1] = (_Float16)r[2 * i8].y;
            hv[2] = (_Float16)r[2 * i8].z;     hv[3] = (_Float16)r[2 * i8].w;
            hv[4] = (_Float16)r[2 * i8 + 1].x; hv[5] = (_Float16)r[2 * i8 + 1].y;
            hv[6] = (_Float16)r[2 * i8 + 1].z; hv[7] = (_Float16)r[2 * i8 + 1].w;
            int byt = srow * 512 + ((q * 64 + i8 * 16) ^ ((srow & 7) << 6));
            *(half8*)((char*)xb + byt) = hv;
        }
    };

    float4 cA[8], cB[8];
    load(cA, 0);

    for (int t = 0; t < nch; ++t) {
        _Float16* xb = xt[t & 1];
        int cnt = seglen - t * ROWS; if (cnt > ROWS) cnt = ROWS;

        if (t & 1) { if (t + 1 < nch) load(cA, t + 1); stage(cB, xb); }
        else       { if (t + 1 < nch) load(cB, t + 1); stage(cA, xb); }
        light_barrier();   // B1: xb staged (prefetch stays in flight)

        // ---- scores: 4 m-tiles x (this wave's 1 n-tile) x 8 k-steps
#pragma unroll
        for (int mt = 0; mt < 4; ++mt) {
            int row = mt * 16 + c;
            const char* base = (const char*)xb + row * 512;
            floatx4 sacc = {0.0f, 0.0f, 0.0f, 0.0f};
#pragma unroll
            for (int ks = 0; ks < 8; ++ks) {
                int byt = (ks * 64 + g * 16) ^ ((row & 7) << 6);
                half8 af = *(const half8*)(base + byt);
                sacc = __builtin_amdgcn_mfma_f32_16x16x32_f16(af, bfr[ks], sacc, 0, 0, 0);
            }
            // D layout: col = c (hidden unit), row-in-tile = g*4 + r
#pragma unroll
            for (int r = 0; r < 4; ++r) {
                float p = fast_tanh(sacc[r] + b1v) * w2v;
                p += __shfl_xor(p, 1); p += __shfl_xor(p, 2);
                p += __shfl_xor(p, 4); p += __shfl_xor(p, 8);
                if (c == 0) pbuf[wv][mt * 16 + g * 4 + r] = p;
            }
        }
        light_barrier();   // B2: pbuf ready

        // ---- weights: w = exp(s), no max shift needed (|s| <~ 11.5)
        if (tid < ROWS) {
            float s = b2v;
#pragma unroll
            for (int w = 0; w < 8; ++w) s += pbuf[w][tid];
            float e = (tid < cnt) ? __expf(s) : 0.0f;
            wbuf[tid] = e;
            zp += e;
        }
        light_barrier();   // B3: wbuf ready

        // ---- pool: thread owns column pcol, rows [prh*32, prh*32+32)
#pragma unroll
        for (int j = 0; j < 32; ++j) {
            int row = prh * 32 + j;
            int byt = row * 512 + ((pcol * 2) ^ ((row & 7) << 6));
            acc = fmaf(wbuf[row], (float)*(const _Float16*)((const char*)xb + byt), acc);
        }
        // no trailing barrier: next stage writes the OTHER buffer; this one
        // is rewritten only after the next B1, which orders our reads.
    }

    // ---- finalize
    __syncthreads();
    float* scr = &pbuf[0][0];        // 512 f32
    scr[tid] = acc;
    if (wv == 0) {                   // z held by wave-0 threads (rows 0..63)
        float z = zp;
        z += __shfl_xor(z, 1);  z += __shfl_xor(z, 2);  z += __shfl_xor(z, 4);
        z += __shfl_xor(z, 8);  z += __shfl_xor(z, 16); z += __shfl_xor(z, 32);
        if (lane == 0) wbuf[0] = z;
    }
    __syncthreads();
    if (tid < H_DIM)
        out[(size_t)b * H_DIM + tid] = (scr[tid] + scr[tid + 256]) / wbuf[0];
}

// ---------------------------------------------------------------- launch
extern "C" void kernel_launch(void* const* d_in, const int* in_sizes, int n_in,
                              void* d_out, int out_size, void* d_ws, size_t ws_size,
                              hipStream_t stream) {
    const float* x    = (const float*)d_in[0];
    const float* W1   = (const float*)d_in[1];
    const float* b1   = (const float*)d_in[2];
    const float* W2   = (const float*)d_in[3];
    const float* b2   = (const float*)d_in[4];
    const int*   batch = (const int*)d_in[5];
    int N = in_sizes[5];
    int B = out_size / H_DIM;

    _Float16* w1h = (_Float16*)d_ws;   // 64KB frag-ordered W1

    prep_w1<<<32768 / 256, 256, 0, stream>>>(W1, w1h);
    fused_kernel<<<B, 512, 0, stream>>>(x, w1h, b1, W2, b2, batch,
                                        (float*)d_out, N);
}

// Round 11
// 381.311 us; speedup vs baseline: 2.4495x; 1.4175x over previous
//
#include <hip/hip_runtime.h>
#include <cstdint>

// AttentionPooling R11 — single-HBM-pass, global_load_lds + counted vmcnt.
//  * x staged DIRECTLY global->LDS (f32) via __builtin_amdgcn_global_load_lds:
//    no staging VGPRs, no cvt on the stage path, no vmcnt-drain at stage.
//  * Counted s_waitcnt vmcnt(4): next chunk's 32KB always in flight across
//    compute (T3/T4 pattern) -> HBM duty cycle structurally high.
//  * Source-side XOR swizzle (lane ^ (row&7), LDS linear; rule #21): MFMA
//    b128 reads and column pool reads at the bank floor.
//  * W1 B-frags in registers (one n-tile per wave, 32 VGPR, loaded once).
//  * exp(s) no-max (|s| <= ||W2||_1+|b2| ~ 11.5, f32-safe; validated R8-R10).
// LDS: 2x32KB xt + 1KB pbuf + misc = ~66.7KB -> 2 blocks/CU (16 waves/CU).

#define H_DIM 256
#define HID   128
#define CHUNK 32

typedef _Float16 half8 __attribute__((ext_vector_type(8)));
typedef float floatx4 __attribute__((ext_vector_type(4)));

__device__ __forceinline__ float fast_tanh(float y) {
    float e2 = __expf(2.0f * y);
    return 1.0f - 2.0f / (e2 + 1.0f);
}

__device__ __forceinline__ void gload_lds16(const float* gp, float* lp) {
    // 16B per lane, per-lane global addr, wave-uniform LDS base (+lane*16).
    __builtin_amdgcn_global_load_lds(
        (const __attribute__((address_space(1))) void*)gp,
        (__attribute__((address_space(3))) void*)lp, 16, 0, 0);
}

// ---------------------------------------------------------------- prep_w1
// idx = ((nt*8 + ks)*64 + lane)*8 + j  <->  W1[k][n], k = ks*32+(lane>>4)*8+j,
// n = nt*16 + (lane&15)
__global__ void prep_w1(const float* __restrict__ W1, _Float16* __restrict__ w1h) {
    int idx = blockIdx.x * blockDim.x + threadIdx.x;
    if (idx >= 8 * 8 * 64 * 8) return;
    int j  = idx & 7;
    int l  = (idx >> 3) & 63;
    int ks = (idx >> 9) & 7;
    int nt = idx >> 12;
    int k = ks * 32 + ((l >> 4) << 3) + j;
    int n = nt * 16 + (l & 15);
    w1h[idx] = (_Float16)W1[k * HID + n];
}

// ---------------------------------------------------------------- fused
// grid = B blocks x 512 threads (8 waves); one graph per block.
__global__ __launch_bounds__(512, 4) void fused_kernel(
    const float* __restrict__ x, const _Float16* __restrict__ w1h,
    const float* __restrict__ b1, const float* __restrict__ W2,
    const float* __restrict__ b2, const int* __restrict__ batch,
    float* __restrict__ out, int N)
{
    __shared__ __align__(16) float xt[2][CHUNK * H_DIM]; // 2 x 32KB f32 tiles
    __shared__ float pbuf[8][CHUNK];                     // per-wave score partials
    __shared__ float wbuf[CHUNK];                        // exp weights
    __shared__ float zsh;

    int tid = threadIdx.x, b = blockIdx.x;
    int wv = tid >> 6, lane = tid & 63, g = lane >> 4, c = lane & 15;
    int pcol = tid & 255, prh = tid >> 8;        // pool: column, row half
    int phi = pcol >> 2, plo = (pcol & 3) << 2;  // pool addr pieces

    // segment bounds (batch sorted)
    int lo = 0, hi = N;
    while (lo < hi) { int m = (lo + hi) >> 1; if (batch[m] < b) lo = m + 1; else hi = m; }
    int start = lo; hi = N;
    while (lo < hi) { int m = (lo + hi) >> 1; if (batch[m] <= b) lo = m + 1; else hi = m; }
    int end = lo;
    int seglen = end - start;
    if (seglen <= 0) {
        if (tid < H_DIM) out[(size_t)b * H_DIM + tid] = 0.0f;
        return;
    }
    int nch = (seglen + CHUNK - 1) / CHUNK;
    int last = end - 1;

    // this wave's W1 n-tile (nt = wv): 8 B-frags in registers, loaded once
    half8 bfr[8];
#pragma unroll
    for (int ks = 0; ks < 8; ++ks)
        bfr[ks] = *(const half8*)&w1h[((wv * 8 + ks) * 64 + lane) * 8];
    float b1v = b1[wv * 16 + c];
    float w2v = W2[wv * 16 + c];
    float b2v = b2[0];

    float acc = 0.0f;   // pooled sum for (pcol, half prh)
    float zp  = 0.0f;   // Z partials (threads 0..31)
    int s7 = c & 7;     // per-lane swizzle key for MFMA reads

    // stage chunk t into buffer bi: wave wv owns rows wv*4..wv*4+3.
    // source-side swizzle: lane loads global 16B-unit (lane ^ (row&7));
    // LDS row r then holds unit u at slot u^(r&7) (involution).
    auto issue_stage = [&](int bi, int t) {
        int base = start + t * CHUNK;
        float* bufp = &xt[bi][0];
#pragma unroll
        for (int i = 0; i < 4; ++i) {
            int r = wv * 4 + i;
            int gr = base + r; if (gr > last) gr = last;   // clamp tail (masked)
            const float* gp = x + (size_t)gr * H_DIM + ((lane ^ (r & 7)) << 2);
            gload_lds16(gp, bufp + r * 256);
        }
    };

    issue_stage(0, 0);
    for (int t = 0; t < nch; ++t) {
        float* xb = &xt[t & 1][0];
        int cnt = seglen - t * CHUNK; if (cnt > CHUNK) cnt = CHUNK;

        if (t + 1 < nch) {
            issue_stage((t + 1) & 1, t + 1);
            asm volatile("s_waitcnt vmcnt(4)" ::: "memory");   // chunk t landed,
        } else {                                               // t+1 in flight
            asm volatile("s_waitcnt vmcnt(0)" ::: "memory");
        }
        __builtin_amdgcn_s_barrier();          // all waves' chunk-t stages done
        __builtin_amdgcn_sched_barrier(0);

        // ---- scores: 2 m-tiles x this wave's n-tile, K=256 in 8 steps
#pragma unroll
        for (int mt = 0; mt < 2; ++mt) {
            int row = mt * 16 + c;
            const char* rb = (const char*)(xb + row * 256);
            floatx4 sacc = {0.0f, 0.0f, 0.0f, 0.0f};
#pragma unroll
            for (int ks = 0; ks < 8; ++ks) {
                int u0 = ks * 8 + g * 2;
                floatx4 fA = *(const floatx4*)(rb + ((u0 ^ s7) << 4));
                floatx4 fB = *(const floatx4*)(rb + (((u0 + 1) ^ s7) << 4));
                half8 af;
                af[0] = (_Float16)fA[0]; af[1] = (_Float16)fA[1];
                af[2] = (_Float16)fA[2]; af[3] = (_Float16)fA[3];
                af[4] = (_Float16)fB[0]; af[5] = (_Float16)fB[1];
                af[6] = (_Float16)fB[2]; af[7] = (_Float16)fB[3];
                sacc = __builtin_amdgcn_mfma_f32_16x16x32_f16(af, bfr[ks], sacc, 0, 0, 0);
            }
            // D layout: col = c (hidden), row-in-tile = g*4 + r
#pragma unroll
            for (int r = 0; r < 4; ++r) {
                float p = fast_tanh(sacc[r] + b1v) * w2v;
                p += __shfl_xor(p, 1); p += __shfl_xor(p, 2);
                p += __shfl_xor(p, 4); p += __shfl_xor(p, 8);
                if (c == 0) pbuf[wv][mt * 16 + g * 4 + r] = p;
            }
        }
        asm volatile("s_waitcnt lgkmcnt(0)" ::: "memory");
        __builtin_amdgcn_s_barrier();          // pbuf ready

        // ---- weights: w = exp(s), no max shift (|s| <~ 11.5)
        if (tid < CHUNK) {
            float s = b2v;
#pragma unroll
            for (int w = 0; w < 8; ++w) s += pbuf[w][tid];
            float e = (tid < cnt) ? __expf(s) : 0.0f;
            wbuf[tid] = e;
            zp += e;
        }
        asm volatile("s_waitcnt lgkmcnt(0)" ::: "memory");
        __builtin_amdgcn_s_barrier();          // wbuf ready

        // ---- pool: thread owns column pcol, rows [prh*16, prh*16+16)
#pragma unroll
        for (int j = 0; j < 16; ++j) {
            int row = prh * 16 + j;
            const char* rb = (const char*)(xb + row * 256);
            float v = *(const float*)(rb + (((phi ^ (row & 7)) << 4) | plo));
            acc = fmaf(wbuf[row], v, acc);
        }
        asm volatile("s_waitcnt lgkmcnt(0)" ::: "memory");
        __builtin_amdgcn_s_barrier();          // buf[t] free for overwrite
    }

    // ---- finalize: combine the two row-halves per column; Z reduce
    float* scr = &xt[0][0];
    scr[tid] = acc;                            // [prh*256 + pcol]
    if (wv == 0) {
        float z = zp;                          // lanes 32-63 hold 0
        z += __shfl_xor(z, 1);  z += __shfl_xor(z, 2);  z += __shfl_xor(z, 4);
        z += __shfl_xor(z, 8);  z += __shfl_xor(z, 16); z += __shfl_xor(z, 32);
        if (lane == 0) zsh = z;
    }
    __syncthreads();
    if (tid < H_DIM)
        out[(size_t)b * H_DIM + tid] = (scr[tid] + scr[tid + 256]) / zsh;
}

// ---------------------------------------------------------------- launch
extern "C" void kernel_launch(void* const* d_in, const int* in_sizes, int n_in,
                              void* d_out, int out_size, void* d_ws, size_t ws_size,
                              hipStream_t stream) {
    const float* x    = (const float*)d_in[0];
    const float* W1   = (const float*)d_in[1];
    const float* b1   = (const float*)d_in[2];
    const float* W2   = (const float*)d_in[3];
    const float* b2   = (const float*)d_in[4];
    const int*   batch = (const int*)d_in[5];
    int N = in_sizes[5];
    int B = out_size / H_DIM;

    _Float16* w1h = (_Float16*)d_ws;   // 64KB frag-ordered W1

    prep_w1<<<32768 / 256, 256, 0, stream>>>(W1, w1h);
    fused_kernel<<<B, 512, 0, stream>>>(x, w1h, b1, W2, b2, batch,
                                        (float*)d_out, N);
}